// Round 6
// baseline (792.383 us; speedup 1.0000x reference)
//
#include <hip/hip_runtime.h>

#define SEQ   2048
#define BATCH 4096
#define HD    32

typedef float f32x2 __attribute__((ext_vector_type(2)));
typedef float f32x4 __attribute__((ext_vector_type(4)));
typedef unsigned int uint2v __attribute__((ext_vector_type(2)));

// ---------------- fast device math ----------------
__device__ __forceinline__ float exp2_fast(float a) {
#if __has_builtin(__builtin_amdgcn_exp2f)
    return __builtin_amdgcn_exp2f(a);
#else
    return exp2f(a);
#endif
}

__device__ __forceinline__ float rcp_fast(float a) {
#if __has_builtin(__builtin_amdgcn_rcpf)
    return __builtin_amdgcn_rcpf(a);
#else
    return 1.0f / a;
#endif
}

// tanh(x) = sign(x) * (1 - e^{-2|x|}) / (1 + e^{-2|x|})
__device__ __forceinline__ float fast_tanh(float v) {
    float ax = fabsf(v);
    float e  = exp2_fast(ax * -2.8853900817779268f);
    float r  = (1.0f - e) * rcp_fast(1.0f + e);
    return copysignf(r, v);
}

// DPP exchange (old=0, bound_ctrl=0, full masks) — HW-verified r0/r2/r5.
// 0xB1 xor-1 ; 0x4E xor-2 ; 0x141 row_half_mirror ; 0x140 row_mirror
template <int CTRL>
__device__ __forceinline__ float dpp_x(float v) {
    return __int_as_float(
        __builtin_amdgcn_update_dpp(0, __float_as_int(v), CTRL, 0xF, 0xF, false));
}

// ds_swizzle xor-16 within 32-lane groups (HW-verified r1/r2).
__device__ __forceinline__ float swz_xor16(float v) {
    return __int_as_float(__builtin_amdgcn_ds_swizzle(__float_as_int(v), 0x401F));
}

// sum over {i, i^16}: permlane16_swap pair holds both values (HW-verified r4).
__device__ __forceinline__ float xsum16(float v) {
#if __has_builtin(__builtin_amdgcn_permlane16_swap)
    uint2v r = __builtin_amdgcn_permlane16_swap(__float_as_uint(v), __float_as_uint(v),
                                                false, false);
    return __uint_as_float(r.x) + __uint_as_float(r.y);
#else
    return v + swz_xor16(v);
#endif
}

// sum over {i, i^32}: permlane32_swap pair holds both values (order-independent
// for a commutative sum). Fallback: ds_bpermute across the full 64-lane wave.
__device__ __forceinline__ float xsum32(float v) {
#if __has_builtin(__builtin_amdgcn_permlane32_swap)
    uint2v r = __builtin_amdgcn_permlane32_swap(__float_as_uint(v), __float_as_uint(v),
                                                false, false);
    return __uint_as_float(r.x) + __uint_as_float(r.y);
#else
    const int addr = (((int)(threadIdx.x & 63) ^ 32) << 2);
    const float o  = __int_as_float(
        __builtin_amdgcn_ds_bpermute(addr, __float_as_int(v)));
    return v + o;
#endif
}

// ---------------- kernel ----------------
// ONE WAVE PER BATCH ELEMENT (64 lanes/elem): 4096 waves -> 4 waves/SIMD,
// double r5's latency-hiding. Lane i: row r=i&31, k-half khalf=i>>5; 16 MACs
// as 8 v_pk_fma. z-reduce = ONE permlane32_swap + add (replaces the 3-level
// DPP tree; both halves produce bit-identical h, so the dual same-address
// LDS write is deterministic and 2-way-free). h broadcast via LDS: per read
// instruction only 2 distinct 16B addresses -> pure bank broadcast.
// e is wave-uniform (readfirstlane) -> x loads + addressing go scalar.
__global__
__attribute__((amdgpu_flat_work_group_size(256, 256)))
__attribute__((amdgpu_waves_per_eu(4)))
void rnn_elman_kernel(
    const float* __restrict__ x, const float* __restrict__ hidden,
    const float* __restrict__ W_ih, const float* __restrict__ b_ih,
    const float* __restrict__ W_hh, const float* __restrict__ b_hh,
    const float* __restrict__ W_fc, const float* __restrict__ b_fc,
    float* __restrict__ out)
{
    __shared__ float sh[4 * 36];     // 4 elements/block (1 per wave), pad to 36

    const int tid   = threadIdx.x;
    const int lane  = tid & 63;
    const int r     = lane & 31;     // owned row
    const int khalf = lane >> 5;     // k-half: [16*khalf, 16*khalf+16)
    const int wid   = tid >> 6;      // wave in block == element in block
    const int e     = __builtin_amdgcn_readfirstlane(blockIdx.x * 4 + wid);

    // ---- weights: row r, own k-half, packed as float2 (8 regs-pairs) ----
    f32x2 wv[8];
    {
        const float* Wr = W_hh + r * HD + khalf * 16;
        #pragma unroll
        for (int m = 0; m < 8; ++m) wv[m] = f32x2{Wr[2 * m], Wr[2 * m + 1]};
    }
    // seed (x-term + bias) only on the khalf=0 copy of each row
    const float seedw = khalf ? 0.f : W_ih[r];
    const float seedb = khalf ? 0.f : (b_ih[r] + b_hh[r]);
    const float wfc   = W_fc[r];
    const float bfc   = b_fc[0];

    float* slot = sh + wid * 36;
    const f32x4* rd = reinterpret_cast<const f32x4*>(slot + khalf * 16);

    // ---- init h into LDS (both halves write identical values) ----
    slot[r] = hidden[e * HD + r];
    __builtin_amdgcn_wave_barrier();
    f32x4 hb[4];
    #pragma unroll
    for (int m = 0; m < 4; ++m) hb[m] = rd[m];

    // ---- x prefetch pipe (distance 4), scalar (e is wave-uniform) ----
    const float* __restrict__ xe = x + e;
    float xq0 = xe[(size_t)0 * BATCH];
    float xq1 = xe[(size_t)1 * BATCH];
    float xq2 = xe[(size_t)2 * BATCH];
    float xq3 = xe[(size_t)3 * BATCH];

    #pragma unroll 4
    for (int t = 0; t < SEQ; ++t) {
        const float xv = xq0;
        xq0 = xq1; xq1 = xq2; xq2 = xq3;
        {
            int tt = t + 4; tt = tt < SEQ ? tt : SEQ - 1;   // uniform clamp
            xq3 = xe[(size_t)tt * BATCH];
        }

        // ---- packed matvec over own 16-k half: 8 pk ops, 2 chains ----
        const f32x2* h2 = reinterpret_cast<const f32x2*>(hb);
        f32x2 p0 = wv[0] * h2[0];
        f32x2 p1 = wv[1] * h2[1];
        p0 += wv[2] * h2[2];
        p1 += wv[3] * h2[3];
        p0 += wv[4] * h2[4];
        p1 += wv[5] * h2[5];
        p0 += wv[6] * h2[6];
        p1 += wv[7] * h2[7];
        const f32x2 ps   = p0 + p1;
        const float seed = fmaf(xv, seedw, seedb);
        const float pmine = (ps.x + ps.y) + seed;

        // ---- cross-half reduce: ONE permlane32_swap + add ----
        const float z = xsum32(pmine);          // both halves: identical bits
        const float h = fast_tanh(z);

        // ---- publish h (dual same-address write, deterministic) ----
        slot[r] = h;
        __builtin_amdgcn_wave_barrier();
        #pragma unroll
        for (int m = 0; m < 4; ++m) hb[m] = rd[m];   // in flight under out tree

        // ---- output projection: DPP tree (16) + permlane16 cross-sum (32) ----
        float u = h * wfc;
        u += dpp_x<0xB1>(u);     // xor-1
        u += dpp_x<0x4E>(u);     // xor-2
        u += dpp_x<0x141>(u);    // 8-group combine
        u += dpp_x<0x140>(u);    // 16-row total
        const float tot = xsum16(u) + bfc;      // rows 0..31 summed, all lanes

        if (lane == 0) out[(size_t)t * BATCH + e] = tot;
    }
}

// ---------------- launch ----------------
extern "C" void kernel_launch(void* const* d_in, const int* in_sizes, int n_in,
                              void* d_out, int out_size, void* d_ws, size_t ws_size,
                              hipStream_t stream) {
    const float* x    = (const float*)d_in[0];
    const float* hid  = (const float*)d_in[1];
    const float* W_ih = (const float*)d_in[2];
    const float* b_ih = (const float*)d_in[3];
    const float* W_hh = (const float*)d_in[4];
    const float* b_hh = (const float*)d_in[5];
    const float* W_fc = (const float*)d_in[6];
    const float* b_fc = (const float*)d_in[7];
    float* out = (float*)d_out;

    dim3 grid(BATCH / 4);    // 1024 blocks -> 4 blocks/CU
    dim3 block(256);         // 4 waves/block, 1 element/wave -> 4 waves/SIMD
    rnn_elman_kernel<<<grid, block, 0, stream>>>(x, hid, W_ih, b_ih, W_hh, b_hh,
                                                 W_fc, b_fc, out);
}

// Round 7
// 772.979 us; speedup vs baseline: 1.0251x; 1.0251x over previous
//
#include <hip/hip_runtime.h>

#define SEQ   2048
#define BATCH 4096
#define HD    32

typedef float f32x2 __attribute__((ext_vector_type(2)));
typedef float f32x4 __attribute__((ext_vector_type(4)));
typedef unsigned int uint2v __attribute__((ext_vector_type(2)));

// ---------------- fast device math ----------------
__device__ __forceinline__ float exp2_fast(float a) {
#if __has_builtin(__builtin_amdgcn_exp2f)
    return __builtin_amdgcn_exp2f(a);
#else
    return exp2f(a);
#endif
}

__device__ __forceinline__ float rcp_fast(float a) {
#if __has_builtin(__builtin_amdgcn_rcpf)
    return __builtin_amdgcn_rcpf(a);
#else
    return 1.0f / a;
#endif
}

// tanh(x) = sign(x) * (1 - e^{-2|x|}) / (1 + e^{-2|x|})
__device__ __forceinline__ float fast_tanh(float v) {
    float ax = fabsf(v);
    float e  = exp2_fast(ax * -2.8853900817779268f);
    float r  = (1.0f - e) * rcp_fast(1.0f + e);
    return copysignf(r, v);
}

// DPP exchange (old=0, bound_ctrl=0, full masks) — HW-verified r0/r2/r5.
// 0xB1 xor-1 ; 0x4E xor-2 ; 0x141 row_half_mirror ; 0x140 row_mirror
template <int CTRL>
__device__ __forceinline__ float dpp_x(float v) {
    return __int_as_float(
        __builtin_amdgcn_update_dpp(0, __float_as_int(v), CTRL, 0xF, 0xF, false));
}

// ds_swizzle xor-16 within 32-lane groups (HW-verified r1/r2).
__device__ __forceinline__ float swz_xor16(float v) {
    return __int_as_float(__builtin_amdgcn_ds_swizzle(__float_as_int(v), 0x401F));
}

// sum over {i, i^16}: permlane16_swap pair holds both values (HW-verified r4).
__device__ __forceinline__ float xsum16(float v) {
#if __has_builtin(__builtin_amdgcn_permlane16_swap)
    uint2v r = __builtin_amdgcn_permlane16_swap(__float_as_uint(v), __float_as_uint(v),
                                                false, false);
    return __uint_as_float(r.x) + __uint_as_float(r.y);
#else
    return v + swz_xor16(v);
#endif
}

// sum over {i, i^32}: permlane32_swap pair holds both values (commutative sum,
// order-independent -> both halves get bit-identical results).
__device__ __forceinline__ float xsum32(float v) {
#if __has_builtin(__builtin_amdgcn_permlane32_swap)
    uint2v r = __builtin_amdgcn_permlane32_swap(__float_as_uint(v), __float_as_uint(v),
                                                false, false);
    return __uint_as_float(r.x) + __uint_as_float(r.y);
#else
    const int addr = (((int)(threadIdx.x & 63) ^ 32) << 2);
    const float o  = __int_as_float(
        __builtin_amdgcn_ds_bpermute(addr, __float_as_int(v)));
    return v + o;
#endif
}

// ---------------- kernel ----------------
// ONE WAVE PER BATCH ELEMENT (64 lanes/elem). 1024-thread blocks hold 16
// CONTIGUOUS elements: 256 blocks -> 1 block/CU -> 16 waves/CU = 4/SIMD
// (r6's occupancy win) while x cache lines are fully used (r6's 4x FETCH
// over-read gone). flat_work_group_size(1024) forces VGPR<=128 by
// construction -- no waves_per_eu hint to trigger r6's VGPR=24 spill squeeze.
// Weight registers are pinned with empty inline-asm so the allocator cannot
// rematerialize their loads into the loop (r6's other pathology).
// Math identical to r6 (harness-verified): lane i handles row r=i&31 over
// k-half khalf=i>>5 as 8 v_pk_fma; z = one permlane32_swap + add; h published
// to LDS by both halves (same addr, same bits); out via DPP tree + permlane16.
__global__
__attribute__((amdgpu_flat_work_group_size(1024, 1024)))
void rnn_elman_kernel(
    const float* __restrict__ x, const float* __restrict__ hidden,
    const float* __restrict__ W_ih, const float* __restrict__ b_ih,
    const float* __restrict__ W_hh, const float* __restrict__ b_hh,
    const float* __restrict__ W_fc, const float* __restrict__ b_fc,
    float* __restrict__ out)
{
    __shared__ float sh[16 * 36];    // 16 elements/block (1 per wave), pad 36

    const int tid   = threadIdx.x;
    const int lane  = tid & 63;
    const int r     = lane & 31;     // owned row
    const int khalf = lane >> 5;     // k-half: [16*khalf, 16*khalf+16)
    const int wid   = tid >> 6;      // wave in block == element in block
    const int e     = __builtin_amdgcn_readfirstlane(blockIdx.x * 16 + wid);

    // ---- weights: row r, own k-half, packed as float2 (8 pairs) ----
    f32x2 wv[8];
    {
        const float* Wr = W_hh + r * HD + khalf * 16;
        #pragma unroll
        for (int m = 0; m < 8; ++m) wv[m] = f32x2{Wr[2 * m], Wr[2 * m + 1]};
    }
    // pin weight registers: opaque to rematerialization/sinking
    #pragma unroll
    for (int m = 0; m < 8; ++m)
        asm volatile("" : "+v"(wv[m].x), "+v"(wv[m].y));

    // seed (x-term + bias) only on the khalf=0 copy of each row
    const float seedw = khalf ? 0.f : W_ih[r];
    const float seedb = khalf ? 0.f : (b_ih[r] + b_hh[r]);
    const float wfc   = W_fc[r];
    const float bfc   = b_fc[0];

    float* slot = sh + wid * 36;
    const f32x4* rd = reinterpret_cast<const f32x4*>(slot + khalf * 16);

    // ---- init h into LDS (both halves write identical values) ----
    slot[r] = hidden[e * HD + r];
    __builtin_amdgcn_wave_barrier();
    f32x4 hb[4];
    #pragma unroll
    for (int m = 0; m < 4; ++m) hb[m] = rd[m];

    // ---- x prefetch pipe (distance 4), scalar (e is wave-uniform) ----
    const float* __restrict__ xe = x + e;
    float xq0 = xe[(size_t)0 * BATCH];
    float xq1 = xe[(size_t)1 * BATCH];
    float xq2 = xe[(size_t)2 * BATCH];
    float xq3 = xe[(size_t)3 * BATCH];

    #pragma unroll 4
    for (int t = 0; t < SEQ; ++t) {
        const float xv = xq0;
        xq0 = xq1; xq1 = xq2; xq2 = xq3;
        {
            int tt = t + 4; tt = tt < SEQ ? tt : SEQ - 1;   // uniform clamp
            xq3 = xe[(size_t)tt * BATCH];
        }

        // ---- packed matvec over own 16-k half: 8 pk ops, 2 chains ----
        const f32x2* h2 = reinterpret_cast<const f32x2*>(hb);
        f32x2 p0 = wv[0] * h2[0];
        f32x2 p1 = wv[1] * h2[1];
        p0 += wv[2] * h2[2];
        p1 += wv[3] * h2[3];
        p0 += wv[4] * h2[4];
        p1 += wv[5] * h2[5];
        p0 += wv[6] * h2[6];
        p1 += wv[7] * h2[7];
        const f32x2 ps    = p0 + p1;
        const float seed  = fmaf(xv, seedw, seedb);
        const float pmine = (ps.x + ps.y) + seed;

        // ---- cross-half reduce: ONE permlane32_swap + add ----
        const float z = xsum32(pmine);          // both halves: identical bits
        const float h = fast_tanh(z);

        // ---- publish h (dual same-address write, deterministic) ----
        slot[r] = h;
        __builtin_amdgcn_wave_barrier();
        #pragma unroll
        for (int m = 0; m < 4; ++m) hb[m] = rd[m];   // in flight under out tree

        // ---- output projection: DPP tree (16) + permlane16 cross-sum (32) ----
        float u = h * wfc;
        u += dpp_x<0xB1>(u);     // xor-1
        u += dpp_x<0x4E>(u);     // xor-2
        u += dpp_x<0x141>(u);    // 8-group combine
        u += dpp_x<0x140>(u);    // 16-row total
        const float tot = xsum16(u) + bfc;      // rows 0..31 summed, all lanes

        if (lane == 0) out[(size_t)t * BATCH + e] = tot;
    }
}

// ---------------- launch ----------------
extern "C" void kernel_launch(void* const* d_in, const int* in_sizes, int n_in,
                              void* d_out, int out_size, void* d_ws, size_t ws_size,
                              hipStream_t stream) {
    const float* x    = (const float*)d_in[0];
    const float* hid  = (const float*)d_in[1];
    const float* W_ih = (const float*)d_in[2];
    const float* b_ih = (const float*)d_in[3];
    const float* W_hh = (const float*)d_in[4];
    const float* b_hh = (const float*)d_in[5];
    const float* W_fc = (const float*)d_in[6];
    const float* b_fc = (const float*)d_in[7];
    float* out = (float*)d_out;

    dim3 grid(BATCH / 16);   // 256 blocks -> 1 block/CU
    dim3 block(1024);        // 16 waves/block, 1 element/wave -> 4 waves/SIMD
    rnn_elman_kernel<<<grid, block, 0, stream>>>(x, hid, W_ih, b_ih, W_hh, b_hh,
                                                 W_fc, b_fc, out);
}

// Round 8
// 768.364 us; speedup vs baseline: 1.0313x; 1.0060x over previous
//
#include <hip/hip_runtime.h>

#define SEQ   2048
#define BATCH 4096
#define HD    32

typedef float f32x2 __attribute__((ext_vector_type(2)));
typedef float f32x4 __attribute__((ext_vector_type(4)));
typedef unsigned int uint2v __attribute__((ext_vector_type(2)));

// ---------------- fast device math ----------------
__device__ __forceinline__ float exp2_fast(float a) {
#if __has_builtin(__builtin_amdgcn_exp2f)
    return __builtin_amdgcn_exp2f(a);
#else
    return exp2f(a);
#endif
}

__device__ __forceinline__ float rcp_fast(float a) {
#if __has_builtin(__builtin_amdgcn_rcpf)
    return __builtin_amdgcn_rcpf(a);
#else
    return 1.0f / a;
#endif
}

// tanh(x) = sign(x) * (1 - e^{-2|x|}) / (1 + e^{-2|x|})
__device__ __forceinline__ float fast_tanh(float v) {
    float ax = fabsf(v);
    float e  = exp2_fast(ax * -2.8853900817779268f);
    float r  = (1.0f - e) * rcp_fast(1.0f + e);
    return copysignf(r, v);
}

// DPP exchange (old=0, bound_ctrl=0, full masks) — HW-verified r0/r2/r5.
// 0xB1 xor-1 ; 0x4E xor-2 ; 0x141 row_half_mirror ; 0x140 row_mirror
template <int CTRL>
__device__ __forceinline__ float dpp_x(float v) {
    return __int_as_float(
        __builtin_amdgcn_update_dpp(0, __float_as_int(v), CTRL, 0xF, 0xF, false));
}

// ds_swizzle xor-16 within 32-lane groups (HW-verified r1/r2).
__device__ __forceinline__ float swz_xor16(float v) {
    return __int_as_float(__builtin_amdgcn_ds_swizzle(__float_as_int(v), 0x401F));
}

// sum over {i, i^16}: permlane16_swap pair holds both values (HW-verified r4).
__device__ __forceinline__ float xsum16(float v) {
#if __has_builtin(__builtin_amdgcn_permlane16_swap)
    uint2v r = __builtin_amdgcn_permlane16_swap(__float_as_uint(v), __float_as_uint(v),
                                                false, false);
    return __uint_as_float(r.x) + __uint_as_float(r.y);
#else
    return v + swz_xor16(v);
#endif
}

// sum over {i, i^32}: permlane32_swap pair holds both values (commutative sum,
// order-independent -> both halves get bit-identical results). HW-verified r6/r7.
__device__ __forceinline__ float xsum32(float v) {
#if __has_builtin(__builtin_amdgcn_permlane32_swap)
    uint2v r = __builtin_amdgcn_permlane32_swap(__float_as_uint(v), __float_as_uint(v),
                                                false, false);
    return __uint_as_float(r.x) + __uint_as_float(r.y);
#else
    const int addr = (((int)(threadIdx.x & 63) ^ 32) << 2);
    const float o  = __int_as_float(
        __builtin_amdgcn_ds_bpermute(addr, __float_as_int(v)));
    return v + o;
#endif
}

// ---------------- kernel ----------------
// ONE WAVE PER BATCH ELEMENT (64 lanes/elem), 16 contiguous elements per
// 1024-thread block: 256 blocks -> 1 block/CU -> 16 waves/CU = 4 waves/SIMD.
// Math identical to harness-verified r6/r7: lane i handles row r=i&31 over
// k-half khalf=i>>5 as 8 v_pk_fma; z = one permlane32_swap + add; h published
// to LDS by both halves (same addr, same bits); out via DPP tree + permlane16.
//
// r8 FIX vs r7: ALL per-lane state is named SSA values. r6/r7 accessed the
// local array hb[4] through a reinterpret_cast'ed f32x2* — type-punned access
// into an alloca defeats SROA, so the whole loop state lived in scratch
// (VGPR_Count=24, WRITE_SIZE inflated 33->54 MB by spill stores, dur 772+).
// No local arrays, no pointer casts onto locals, no asm pins, no
// waves_per_eu hints. Weight pairs w0..w7 and h quads A..D are plain SSA.
__global__
__attribute__((amdgpu_flat_work_group_size(1024, 1024)))
void rnn_elman_kernel(
    const float* __restrict__ x, const float* __restrict__ hidden,
    const float* __restrict__ W_ih, const float* __restrict__ b_ih,
    const float* __restrict__ W_hh, const float* __restrict__ b_hh,
    const float* __restrict__ W_fc, const float* __restrict__ b_fc,
    float* __restrict__ out)
{
    __shared__ float sh[16 * 36];    // 16 elements/block (1 per wave), pad 36

    const int tid   = threadIdx.x;
    const int lane  = tid & 63;
    const int r     = lane & 31;     // owned row
    const int khalf = lane >> 5;     // k-half: [16*khalf, 16*khalf+16)
    const int wid   = tid >> 6;      // wave in block == element in block
    const int e     = __builtin_amdgcn_readfirstlane(blockIdx.x * 16 + wid);

    // ---- weights: row r, own k-half, eight named float2 pairs ----
    const float* Wr = W_hh + r * HD + khalf * 16;
    const f32x2 w0 = f32x2{Wr[0],  Wr[1]};
    const f32x2 w1 = f32x2{Wr[2],  Wr[3]};
    const f32x2 w2 = f32x2{Wr[4],  Wr[5]};
    const f32x2 w3 = f32x2{Wr[6],  Wr[7]};
    const f32x2 w4 = f32x2{Wr[8],  Wr[9]};
    const f32x2 w5 = f32x2{Wr[10], Wr[11]};
    const f32x2 w6 = f32x2{Wr[12], Wr[13]};
    const f32x2 w7 = f32x2{Wr[14], Wr[15]};

    // seed (x-term + bias) only on the khalf=0 copy of each row
    const float seedw = khalf ? 0.f : W_ih[r];
    const float seedb = khalf ? 0.f : (b_ih[r] + b_hh[r]);
    const float wfc   = W_fc[r];
    const float bfc   = b_fc[0];

    float* slot = sh + wid * 36;
    const f32x4* rd = reinterpret_cast<const f32x4*>(slot + khalf * 16);

    // ---- init h into LDS (both halves write identical values) ----
    slot[r] = hidden[e * HD + r];
    __builtin_amdgcn_wave_barrier();
    f32x4 A = rd[0], B = rd[1], C = rd[2], D = rd[3];   // named SSA h state

    // ---- x prefetch pipe (distance 4), e is wave-uniform ----
    const float* __restrict__ xe = x + e;
    float xq0 = xe[(size_t)0 * BATCH];
    float xq1 = xe[(size_t)1 * BATCH];
    float xq2 = xe[(size_t)2 * BATCH];
    float xq3 = xe[(size_t)3 * BATCH];

    #pragma unroll 4
    for (int t = 0; t < SEQ; ++t) {
        const float xv = xq0;
        xq0 = xq1; xq1 = xq2; xq2 = xq3;
        {
            int tt = t + 4; tt = tt < SEQ ? tt : SEQ - 1;   // uniform clamp
            xq3 = xe[(size_t)tt * BATCH];
        }

        // ---- packed matvec over own 16-k half: 8 pk ops, 2 chains ----
        f32x2 p0 = w0 * f32x2{A.x, A.y};
        f32x2 p1 = w1 * f32x2{A.z, A.w};
        p0 += w2 * f32x2{B.x, B.y};
        p1 += w3 * f32x2{B.z, B.w};
        p0 += w4 * f32x2{C.x, C.y};
        p1 += w5 * f32x2{C.z, C.w};
        p0 += w6 * f32x2{D.x, D.y};
        p1 += w7 * f32x2{D.z, D.w};
        const f32x2 ps    = p0 + p1;
        const float seed  = fmaf(xv, seedw, seedb);
        const float pmine = (ps.x + ps.y) + seed;

        // ---- cross-half reduce: ONE permlane32_swap + add ----
        const float z = xsum32(pmine);          // both halves: identical bits
        const float h = fast_tanh(z);

        // ---- publish h (dual same-address write, deterministic) ----
        slot[r] = h;
        __builtin_amdgcn_wave_barrier();
        A = rd[0]; B = rd[1]; C = rd[2]; D = rd[3];   // in flight under out tree

        // ---- output projection: DPP tree (16) + permlane16 cross-sum (32) ----
        float u = h * wfc;
        u += dpp_x<0xB1>(u);     // xor-1
        u += dpp_x<0x4E>(u);     // xor-2
        u += dpp_x<0x141>(u);    // 8-group combine
        u += dpp_x<0x140>(u);    // 16-row total
        const float tot = xsum16(u) + bfc;      // rows 0..31 summed, all lanes

        if (lane == 0) out[(size_t)t * BATCH + e] = tot;
    }
}

// ---------------- launch ----------------
extern "C" void kernel_launch(void* const* d_in, const int* in_sizes, int n_in,
                              void* d_out, int out_size, void* d_ws, size_t ws_size,
                              hipStream_t stream) {
    const float* x    = (const float*)d_in[0];
    const float* hid  = (const float*)d_in[1];
    const float* W_ih = (const float*)d_in[2];
    const float* b_ih = (const float*)d_in[3];
    const float* W_hh = (const float*)d_in[4];
    const float* b_hh = (const float*)d_in[5];
    const float* W_fc = (const float*)d_in[6];
    const float* b_fc = (const float*)d_in[7];
    float* out = (float*)d_out;

    dim3 grid(BATCH / 16);   // 256 blocks -> 1 block/CU
    dim3 block(1024);        // 16 waves/block, 1 element/wave -> 4 waves/SIMD
    rnn_elman_kernel<<<grid, block, 0, stream>>>(x, hid, W_ih, b_ih, W_hh, b_hh,
                                                 W_fc, b_fc, out);
}